// Round 4
// baseline (539.529 us; speedup 1.0000x reference)
//
#include <hip/hip_runtime.h>
#include <math.h>

#define NMS_THR 0.3f

__device__ __forceinline__ float fmul(float a, float b){ return __fmul_rn(a,b); }
__device__ __forceinline__ float fadd(float a, float b){ return __fadd_rn(a,b); }
__device__ __forceinline__ float fsub(float a, float b){ return __fsub_rn(a,b); }

__device__ __forceinline__ unsigned long long rdlane64(unsigned int lo, unsigned int hi, int a) {
    unsigned long long l = (unsigned int)__builtin_amdgcn_readlane((int)lo, a);
    unsigned long long h = (unsigned int)__builtin_amdgcn_readlane((int)hi, a);
    return (h << 32) | l;
}

// K1: per-row softmax max/sum + argmax + per-class regression decode. One wave per row.
__global__ __launch_bounds__(256) void k_decode(
    const float* __restrict__ prop, const float* __restrict__ reg,
    const float* __restrict__ clss, const float* __restrict__ stds,
    const int* __restrict__ imgsz,
    float* __restrict__ boxes, float* __restrict__ key,
    float* __restrict__ score, int* __restrict__ cls,
    int N, int C)
{
    int wid  = threadIdx.x >> 6;
    int lane = threadIdx.x & 63;
    int n = blockIdx.x * 4 + wid;
    if (n >= N) return;
    const float* row = clss + (long)n * C;
    float ninf = -__builtin_inff();
    float x0 = (lane < C)      ? row[lane]      : ninf;
    float x1 = (lane + 64 < C) ? row[lane + 64] : ninf;
    float m = fmaxf(x0, x1);
    for (int o = 32; o > 0; o >>= 1) m = fmaxf(m, __shfl_xor(m, o));
    float e0 = (lane < C)      ? expf(x0 - m) : 0.0f;
    float e1 = (lane + 64 < C) ? expf(x1 - m) : 0.0f;
    float s = e0 + e1;
    for (int o = 32; o > 0; o >>= 1) s += __shfl_xor(s, o);
    float bv; int bi;
    if (e0 >= e1) { bv = e0; bi = lane; } else { bv = e1; bi = lane + 64; }
    for (int o = 32; o > 0; o >>= 1) {
        float ov = __shfl_xor(bv, o);
        int   oi = __shfl_xor(bi, o);
        if (ov > bv || (ov == bv && oi < bi)) { bv = ov; bi = oi; }
    }
    if (lane == 0) {
        float sc = 1.0f / s;
        int   c  = bi;
        int   valid = (c != 0);
        float p0 = prop[n*4+0], p1 = prop[n*4+1], p2 = prop[n*4+2], p3 = prop[n*4+3];
        float w  = fsub(p2, p0), h = fsub(p3, p1);
        float cx = fadd(p0, fmul(0.5f, w));
        float cy = fadd(p1, fmul(0.5f, h));
        const float* rr = reg + (long)n * C * 4 + (long)c * 4;
        float t0 = fmul(rr[0], stds[0]);
        float t1 = fmul(rr[1], stds[1]);
        float t2 = fmul(rr[2], stds[2]);
        float t3 = fmul(rr[3], stds[3]);
        float px = fadd(cx, fmul(w, t0));
        float py = fadd(cy, fmul(h, t1));
        float pw = fmul(w, expf(t2));
        float ph = fmul(h, expf(t3));
        float hi = (float)(imgsz[0] - 1);
        float bx1 = fminf(fmaxf(fsub(px, fmul(0.5f, pw)), 0.0f), hi);
        float by1 = fminf(fmaxf(fsub(py, fmul(0.5f, ph)), 0.0f), hi);
        float bx2 = fminf(fmaxf(fadd(px, fmul(0.5f, pw)), 0.0f), hi);
        float by2 = fminf(fmaxf(fadd(py, fmul(0.5f, ph)), 0.0f), hi);
        boxes[n*4+0]=bx1; boxes[n*4+1]=by1; boxes[n*4+2]=bx2; boxes[n*4+3]=by2;
        score[n] = sc;
        cls[n]   = c;
        key[n]   = valid ? sc : ninf;
    }
}

// K2: stable descending rank sort. 64 rows/block, 4 j-strips of 256 threads.
// Block 0 additionally computes nValid (count of keys != -inf).
__global__ __launch_bounds__(256) void k_rank(
    const float* __restrict__ key, const float* __restrict__ boxes,
    float* __restrict__ boxesSorted, float* __restrict__ areaSorted,
    float* __restrict__ keySorted, int* __restrict__ rank,
    int* __restrict__ nValidPtr, int N)
{
    extern __shared__ float lkey[];     // N floats
    __shared__ int part[256];
    int tid = threadIdx.x;
    for (int j = tid; j < N; j += 256) lkey[j] = key[j];
    __syncthreads();

    int i = blockIdx.x * 64 + (tid & 63);
    int s = tid >> 6;
    int Q = (N + 3) >> 2;
    int r_part = 0;
    if (i < N) {
        float ki = lkey[i];
        int j0 = s * Q, j1 = min(N, j0 + Q);
        for (int j = j0; j < j1; ++j) {
            float kj = lkey[j];
            r_part += (kj > ki) || (kj == ki && j < i);   // stable
        }
    }
    part[tid] = r_part;
    __syncthreads();

    if (tid < 64 && i < N) {
        int r = part[tid] + part[tid+64] + part[tid+128] + part[tid+192];
        float ki = lkey[i];
        rank[i] = r;
        float b0 = boxes[i*4+0], b1 = boxes[i*4+1], b2 = boxes[i*4+2], b3 = boxes[i*4+3];
        boxesSorted[r*4+0]=b0; boxesSorted[r*4+1]=b1; boxesSorted[r*4+2]=b2; boxesSorted[r*4+3]=b3;
        areaSorted[r] = fmul(fsub(b2,b0), fsub(b3,b1));
        keySorted[r]  = ki;
    }

    if (blockIdx.x == 0) {
        __syncthreads();
        float ninf = -__builtin_inff();
        int inv = 0;
        for (int j = tid; j < N; j += 256) inv += (lkey[j] == ninf);
        part[tid] = inv;
        __syncthreads();
        if (tid == 0) {
            int t = 0;
            for (int q = 0; q < 256; ++q) t += part[q];
            nValidPtr[0] = N - t;
        }
    }
}

// K3: suppression bitmask, ROW-MAJOR padded: mask[i*Wpad + w]; rows 16B-aligned.
// diag[i] = word i>>6 of row i; sdiag[i] = word (i>>6)+1 (0 if out of range).
__global__ __launch_bounds__(256) void k_mask(
    const float* __restrict__ bs, const float* __restrict__ areas,
    const float* __restrict__ keySorted, unsigned long long* __restrict__ mask,
    unsigned long long* __restrict__ diag, unsigned long long* __restrict__ sdiag,
    int N, int W, int Wpad)
{
    int wid  = threadIdx.x >> 6;
    int lane = threadIdx.x & 63;
    int i = blockIdx.x * 4 + wid;
    if (i >= N) return;
    if (keySorted[i] == -__builtin_inff()) return;   // invalid row: never read
    float ax1 = bs[i*4+0], ay1 = bs[i*4+1], ax2 = bs[i*4+2], ay2 = bs[i*4+3];
    float aa  = areas[i];
    int w0 = i >> 6;
    if (lane == 0 && w0 + 1 >= W) sdiag[i] = 0ULL;
    for (int w = w0; w < W; ++w) {
        int j = w*64 + lane;
        int bit = 0;
        if (j < N && j > i) {
            float bx1 = bs[j*4+0], by1 = bs[j*4+1], bx2 = bs[j*4+2], by2 = bs[j*4+3];
            float ba  = areas[j];
            float ix1 = fmaxf(ax1,bx1), iy1 = fmaxf(ay1,by1);
            float ix2 = fminf(ax2,bx2), iy2 = fminf(ay2,by2);
            float iw = fmaxf(fsub(ix2,ix1), 0.0f);
            float ih = fmaxf(fsub(iy2,iy1), 0.0f);
            float inter = fmul(iw, ih);
            float denom = fadd(fsub(fadd(aa, ba), inter), 1e-9f);
            float iou = inter / denom;
            bit = (iou > NMS_THR) ? 1 : 0;
        }
        unsigned long long bm = __ballot(bit);
        if (lane == 0) {
            mask[(long)i*Wpad + w] = bm;
            if (w == w0)     diag[i]  = bm;
            if (w == w0 + 1) sdiag[i] = bm;
        }
    }
}

// K4: chunked greedy scan, ONE wave on the whole GPU -> take all the VGPRs
// (__launch_bounds__(64,1)). removed-bitmap distributed: lane L owns words
// 2L (rx) and 2L+1 (ry) -> one dwordx4 load per kept row. Kept-row loads park
// one chunk deep in pend[16] (64 VGPRs, register-resident now); next chunk's
// inc comes from sdiag so resolve never waits on row loads.
__global__ __launch_bounds__(64, 1) void k_scan(
    const unsigned long long* __restrict__ mask,
    const unsigned long long* __restrict__ diag,
    const unsigned long long* __restrict__ sdiag,
    const int* __restrict__ nValidPtr,
    int* __restrict__ keepSorted, int N, int W, int Wpad)
{
    int lane = threadIdx.x;
    for (int i = lane; i < N; i += 64) keepSorted[i] = 0;
    int nValid = nValidPtr[0];
    int nChunks = (nValid + 63) >> 6;

    unsigned long long rx = 0ULL, ry = 0ULL;
    bool okx = (2*lane)     < W;
    bool oky = (2*lane + 1) < W;

    unsigned long long px[16], py[16];
#pragma unroll
    for (int q = 0; q < 16; ++q) { px[q] = 0ULL; py[q] = 0ULL; }

    unsigned long long D = 0ULL, S = 0ULL;
    if (lane < nValid) { D = diag[lane]; S = sdiag[lane]; }
    unsigned long long inc = 0ULL;

    for (int c = 0; c < nChunks; ++c) {
        int base = c << 6;
        // prefetch next chunk's diag/sdiag (coalesced, off critical path)
        unsigned long long Dn = 0ULL, Sn = 0ULL;
        int nrow = base + 64 + lane;
        if (c + 1 < nChunks && nrow < nValid) { Dn = diag[nrow]; Sn = sdiag[nrow]; }

        int nv = nValid - base;
        unsigned long long validBits = (nv >= 64) ? ~0ULL : ((1ULL << nv) - 1ULL);
        unsigned long long cand = validBits & ~inc;
        unsigned long long keepM = 0ULL;
        unsigned int Dlo = (unsigned int)D, Dhi = (unsigned int)(D >> 32);
        while (cand) {                      // pure dependence chain
            int a = __builtin_ctzll(cand);
            keepM |= (1ULL << a);
            unsigned long long Da = rdlane64(Dlo, Dhi, a);
            cand &= ~(1ULL << a) & ~Da;
        }
        if (base + lane < N) keepSorted[base + lane] = (int)((keepM >> lane) & 1ULL);

        // sacc: OR of sdiag over kept lanes, wave reduce (off critical path)
        unsigned long long sv = ((keepM >> lane) & 1ULL) ? S : 0ULL;
        for (int o = 32; o > 0; o >>= 1) sv |= __shfl_xor(sv, o);

        // OR previous chunk's pending row masks (waitcnt hidden by resolve)
        {
            unsigned long long ax = 0ULL, ay = 0ULL;
#pragma unroll
            for (int q = 0; q < 16; ++q) { ax |= px[q]; ay |= py[q]; }
            rx |= ax; ry |= ay;
        }

        // issue this chunk's kept-row loads into pending (1 dwordx4/lane/row)
        unsigned long long kb = keepM;
#pragma unroll
        for (int q = 0; q < 16; ++q) {
            unsigned long long vx = 0ULL, vy = 0ULL;
            if (kb) {
                int a = __builtin_ctzll(kb); kb &= kb - 1ULL;
                const ulonglong2* rp = (const ulonglong2*)(mask + (size_t)(base + a) * Wpad);
                if (okx) {
                    ulonglong2 v = rp[lane];
                    vx = v.x; vy = oky ? v.y : 0ULL;
                }
            }
            px[q] = vx; py[q] = vy;
        }
        while (kb) {   // overflow (>16 kept in one chunk): OR immediately
            int a = __builtin_ctzll(kb); kb &= kb - 1ULL;
            const ulonglong2* rp = (const ulonglong2*)(mask + (size_t)(base + a) * Wpad);
            if (okx) {
                ulonglong2 v = rp[lane];
                rx |= v.x; if (oky) ry |= v.y;
            }
        }

        // inc for chunk c+1: word c+1 of removed-map.
        // chunks <= c-1 are in rx/ry; chunk c's contribution arrives via sdiag.
        int wn = c + 1;
        unsigned long long rown = (wn & 1) ? ry : rx;   // uniform select
        unsigned long long rw = __shfl(rown, wn >> 1);
        inc = rw | sv;

        D = Dn; S = Sn;
    }
}

// K5: write outputs in original order: boxes*m, score*m, float(cls*keep).
__global__ __launch_bounds__(256) void k_out(
    const float* __restrict__ boxes, const float* __restrict__ score,
    const int* __restrict__ cls, const int* __restrict__ rank,
    const int* __restrict__ keepSorted,
    float* __restrict__ out, int N)
{
    int n = blockIdx.x * blockDim.x + threadIdx.x;
    if (n >= N) return;
    int k = keepSorted[rank[n]];
    float m = (float)k;
    out[n*4+0] = boxes[n*4+0]*m;
    out[n*4+1] = boxes[n*4+1]*m;
    out[n*4+2] = boxes[n*4+2]*m;
    out[n*4+3] = boxes[n*4+3]*m;
    out[(long)N*4 + n] = score[n]*m;
    out[(long)N*5 + n] = (float)(cls[n] * k);
}

extern "C" void kernel_launch(void* const* d_in, const int* in_sizes, int n_in,
                              void* d_out, int out_size, void* d_ws, size_t ws_size,
                              hipStream_t stream) {
    const float* prop = (const float*)d_in[0];
    const float* reg  = (const float*)d_in[1];
    const float* clss = (const float*)d_in[2];
    const float* stds = (const float*)d_in[3];
    const int*   img  = (const int*)d_in[4];

    int N = in_sizes[0] / 4;
    int C = in_sizes[2] / N;
    int W = (N + 63) / 64;
    int Wpad = (W + 1) & ~1;          // even -> 16B rows

    char* ws = (char*)d_ws;
    size_t off = 0;
    float* boxes       = (float*)(ws + off); off += (size_t)N*4*sizeof(float);
    float* key         = (float*)(ws + off); off += (size_t)N*sizeof(float);
    float* score       = (float*)(ws + off); off += (size_t)N*sizeof(float);
    int*   cls         = (int*)  (ws + off); off += (size_t)N*sizeof(int);
    int*   rank        = (int*)  (ws + off); off += (size_t)N*sizeof(int);
    float* boxesSorted = (float*)(ws + off); off += (size_t)N*4*sizeof(float);
    float* areaSorted  = (float*)(ws + off); off += (size_t)N*sizeof(float);
    float* keySorted   = (float*)(ws + off); off += (size_t)N*sizeof(float);
    int*   keepSorted  = (int*)  (ws + off); off += (size_t)N*sizeof(int);
    int*   nValid      = (int*)  (ws + off); off += sizeof(int);
    off = (off + 15) & ~(size_t)15;   // 16B-align mask rows
    unsigned long long* mask  = (unsigned long long*)(ws + off);
    off += (size_t)N * Wpad * sizeof(unsigned long long);
    unsigned long long* diag  = (unsigned long long*)(ws + off);
    off += (size_t)N * sizeof(unsigned long long);
    unsigned long long* sdiag = (unsigned long long*)(ws + off);
    off += (size_t)N * sizeof(unsigned long long);
    (void)ws_size; (void)out_size; (void)n_in;

    int rowBlocks  = (N + 3) / 4;
    int thrBlocks  = (N + 255) / 256;
    int rankBlocks = (N + 63) / 64;

    k_decode<<<rowBlocks, 256, 0, stream>>>(prop, reg, clss, stds, img,
                                            boxes, key, score, cls, N, C);
    k_rank<<<rankBlocks, 256, (size_t)N*sizeof(float), stream>>>(key, boxes,
                                            boxesSorted, areaSorted, keySorted, rank, nValid, N);
    k_mask<<<rowBlocks, 256, 0, stream>>>(boxesSorted, areaSorted, keySorted,
                                          mask, diag, sdiag, N, W, Wpad);
    k_scan<<<1, 64, 0, stream>>>(mask, diag, sdiag, nValid, keepSorted, N, W, Wpad);
    k_out<<<thrBlocks, 256, 0, stream>>>(boxes, score, cls, rank, keepSorted,
                                         (float*)d_out, N);
}

// Round 5
// 381.525 us; speedup vs baseline: 1.4141x; 1.4141x over previous
//
#include <hip/hip_runtime.h>
#include <math.h>

#define NMS_THR 0.3f

__device__ __forceinline__ float fmul(float a, float b){ return __fmul_rn(a,b); }
__device__ __forceinline__ float fadd(float a, float b){ return __fadd_rn(a,b); }
__device__ __forceinline__ float fsub(float a, float b){ return __fsub_rn(a,b); }

__device__ __forceinline__ unsigned long long rdlane64(unsigned int lo, unsigned int hi, int a) {
    unsigned long long l = (unsigned int)__builtin_amdgcn_readlane((int)lo, a);
    unsigned long long h = (unsigned int)__builtin_amdgcn_readlane((int)hi, a);
    return (h << 32) | l;
}

// K1: per-row softmax max/sum + argmax + per-class regression decode. One wave per row.
__global__ __launch_bounds__(256) void k_decode(
    const float* __restrict__ prop, const float* __restrict__ reg,
    const float* __restrict__ clss, const float* __restrict__ stds,
    const int* __restrict__ imgsz,
    float* __restrict__ boxes, float* __restrict__ key,
    float* __restrict__ score, int* __restrict__ cls,
    int N, int C)
{
    int wid  = threadIdx.x >> 6;
    int lane = threadIdx.x & 63;
    int n = blockIdx.x * 4 + wid;
    if (n >= N) return;
    const float* row = clss + (long)n * C;
    float ninf = -__builtin_inff();
    float x0 = (lane < C)      ? row[lane]      : ninf;
    float x1 = (lane + 64 < C) ? row[lane + 64] : ninf;
    float m = fmaxf(x0, x1);
    for (int o = 32; o > 0; o >>= 1) m = fmaxf(m, __shfl_xor(m, o));
    float e0 = (lane < C)      ? expf(x0 - m) : 0.0f;
    float e1 = (lane + 64 < C) ? expf(x1 - m) : 0.0f;
    float s = e0 + e1;
    for (int o = 32; o > 0; o >>= 1) s += __shfl_xor(s, o);
    float bv; int bi;
    if (e0 >= e1) { bv = e0; bi = lane; } else { bv = e1; bi = lane + 64; }
    for (int o = 32; o > 0; o >>= 1) {
        float ov = __shfl_xor(bv, o);
        int   oi = __shfl_xor(bi, o);
        if (ov > bv || (ov == bv && oi < bi)) { bv = ov; bi = oi; }
    }
    if (lane == 0) {
        float sc = 1.0f / s;
        int   c  = bi;
        int   valid = (c != 0);
        float p0 = prop[n*4+0], p1 = prop[n*4+1], p2 = prop[n*4+2], p3 = prop[n*4+3];
        float w  = fsub(p2, p0), h = fsub(p3, p1);
        float cx = fadd(p0, fmul(0.5f, w));
        float cy = fadd(p1, fmul(0.5f, h));
        const float* rr = reg + (long)n * C * 4 + (long)c * 4;
        float t0 = fmul(rr[0], stds[0]);
        float t1 = fmul(rr[1], stds[1]);
        float t2 = fmul(rr[2], stds[2]);
        float t3 = fmul(rr[3], stds[3]);
        float px = fadd(cx, fmul(w, t0));
        float py = fadd(cy, fmul(h, t1));
        float pw = fmul(w, expf(t2));
        float ph = fmul(h, expf(t3));
        float hi = (float)(imgsz[0] - 1);
        float bx1 = fminf(fmaxf(fsub(px, fmul(0.5f, pw)), 0.0f), hi);
        float by1 = fminf(fmaxf(fsub(py, fmul(0.5f, ph)), 0.0f), hi);
        float bx2 = fminf(fmaxf(fadd(px, fmul(0.5f, pw)), 0.0f), hi);
        float by2 = fminf(fmaxf(fadd(py, fmul(0.5f, ph)), 0.0f), hi);
        boxes[n*4+0]=bx1; boxes[n*4+1]=by1; boxes[n*4+2]=bx2; boxes[n*4+3]=by2;
        score[n] = sc;
        cls[n]   = c;
        key[n]   = valid ? sc : ninf;
    }
}

// K2: stable descending rank sort. 64 rows/block, 4 j-strips of 256 threads.
// Block 0 additionally computes nValid (count of keys != -inf).
__global__ __launch_bounds__(256) void k_rank(
    const float* __restrict__ key, const float* __restrict__ boxes,
    float* __restrict__ boxesSorted, float* __restrict__ areaSorted,
    float* __restrict__ keySorted, int* __restrict__ rank,
    int* __restrict__ nValidPtr, int N)
{
    extern __shared__ float lkey[];     // N floats
    __shared__ int part[256];
    int tid = threadIdx.x;
    for (int j = tid; j < N; j += 256) lkey[j] = key[j];
    __syncthreads();

    int i = blockIdx.x * 64 + (tid & 63);
    int s = tid >> 6;
    int Q = (N + 3) >> 2;
    int r_part = 0;
    if (i < N) {
        float ki = lkey[i];
        int j0 = s * Q, j1 = min(N, j0 + Q);
        for (int j = j0; j < j1; ++j) {
            float kj = lkey[j];
            r_part += (kj > ki) || (kj == ki && j < i);   // stable
        }
    }
    part[tid] = r_part;
    __syncthreads();

    if (tid < 64 && i < N) {
        int r = part[tid] + part[tid+64] + part[tid+128] + part[tid+192];
        float ki = lkey[i];
        rank[i] = r;
        float b0 = boxes[i*4+0], b1 = boxes[i*4+1], b2 = boxes[i*4+2], b3 = boxes[i*4+3];
        boxesSorted[r*4+0]=b0; boxesSorted[r*4+1]=b1; boxesSorted[r*4+2]=b2; boxesSorted[r*4+3]=b3;
        areaSorted[r] = fmul(fsub(b2,b0), fsub(b3,b1));
        keySorted[r]  = ki;
    }

    if (blockIdx.x == 0) {
        __syncthreads();
        float ninf = -__builtin_inff();
        int inv = 0;
        for (int j = tid; j < N; j += 256) inv += (lkey[j] == ninf);
        part[tid] = inv;
        __syncthreads();
        if (tid == 0) {
            int t = 0;
            for (int q = 0; q < 256; ++q) t += part[q];
            nValidPtr[0] = N - t;
        }
    }
}

// K3: suppression bitmask, ROW-MAJOR padded: mask[i*Wpad + w]; rows 16B-aligned.
// diag[i] = word i>>6 of row i; sdiag[i] = word (i>>6)+1 (0 if out of range).
__global__ __launch_bounds__(256) void k_mask(
    const float* __restrict__ bs, const float* __restrict__ areas,
    const float* __restrict__ keySorted, unsigned long long* __restrict__ mask,
    unsigned long long* __restrict__ diag, unsigned long long* __restrict__ sdiag,
    int N, int W, int Wpad)
{
    int wid  = threadIdx.x >> 6;
    int lane = threadIdx.x & 63;
    int i = blockIdx.x * 4 + wid;
    if (i >= N) return;
    if (keySorted[i] == -__builtin_inff()) return;   // invalid row: never read
    float ax1 = bs[i*4+0], ay1 = bs[i*4+1], ax2 = bs[i*4+2], ay2 = bs[i*4+3];
    float aa  = areas[i];
    int w0 = i >> 6;
    if (lane == 0 && w0 + 1 >= W) sdiag[i] = 0ULL;
    for (int w = w0; w < W; ++w) {
        int j = w*64 + lane;
        int bit = 0;
        if (j < N && j > i) {
            float bx1 = bs[j*4+0], by1 = bs[j*4+1], bx2 = bs[j*4+2], by2 = bs[j*4+3];
            float ba  = areas[j];
            float ix1 = fmaxf(ax1,bx1), iy1 = fmaxf(ay1,by1);
            float ix2 = fminf(ax2,bx2), iy2 = fminf(ay2,by2);
            float iw = fmaxf(fsub(ix2,ix1), 0.0f);
            float ih = fmaxf(fsub(iy2,iy1), 0.0f);
            float inter = fmul(iw, ih);
            float denom = fadd(fsub(fadd(aa, ba), inter), 1e-9f);
            float iou = inter / denom;
            bit = (iou > NMS_THR) ? 1 : 0;
        }
        unsigned long long bm = __ballot(bit);
        if (lane == 0) {
            mask[(long)i*Wpad + w] = bm;
            if (w == w0)     diag[i]  = bm;
            if (w == w0 + 1) sdiag[i] = bm;
        }
    }
}

// K4: wave-specialized chunked greedy scan. One block, 2 waves.
//  wave 0 (resolver): per chunk, scalar ctz+readlane chain over diag; computes
//    sacc = OR of sdiag over kept rows (word c+1 contribution of chunk c).
//  wave 1 (accumulator): lane L owns words 2L,2L+1; per kept row ORs one
//    ulonglong2 (coalesced) into acc, SYNCHRONOUSLY — its stall overlaps
//    wave 0's next resolve. Publishes word c+1 to LDS before issuing chunk-c
//    loads, so inc never waits on in-flight memory.
//  inc_c = ldsInc(kept rows <= c-2, memory) | sacc_prev(kept rows of c-1).
__global__ __launch_bounds__(128, 1) void k_scan(
    const unsigned long long* __restrict__ mask,
    const unsigned long long* __restrict__ diag,
    const unsigned long long* __restrict__ sdiag,
    const int* __restrict__ nValidPtr,
    int* __restrict__ keepSorted, int N, int W, int Wpad)
{
    __shared__ unsigned long long ldsInc;
    __shared__ unsigned long long ldsKeep;
    int tid  = threadIdx.x;
    int wid  = tid >> 6;
    int lane = tid & 63;
    for (int i = tid; i < N; i += 128) keepSorted[i] = 0;
    if (tid == 0) { ldsInc = 0ULL; ldsKeep = 0ULL; }
    __syncthreads();

    int nValid  = nValidPtr[0];
    int nChunks = (nValid + 63) >> 6;

    // wave 0 state
    unsigned long long D = 0ULL, S = 0ULL, sacc_prev = 0ULL;
    if (wid == 0 && lane < nValid) { D = diag[lane]; S = sdiag[lane]; }
    // wave 1 state
    unsigned long long accx = 0ULL, accy = 0ULL;
    bool w1ok = (wid == 1) && (2*lane < W);

    for (int c = 0; c < nChunks; ++c) {
        int base = c << 6;
        if (wid == 0) {
            // prefetch next chunk's diag/sdiag (one chunk of slack)
            unsigned long long Dn = 0ULL, Sn = 0ULL;
            int nr = base + 64 + lane;
            if (c + 1 < nChunks && nr < nValid) { Dn = diag[nr]; Sn = sdiag[nr]; }

            unsigned long long inc = ldsInc | sacc_prev;
            int nv = nValid - base;
            unsigned long long validBits = (nv >= 64) ? ~0ULL : ((1ULL << nv) - 1ULL);
            unsigned long long cand = validBits & ~inc;
            unsigned long long keepM = 0ULL, sacc = 0ULL;
            unsigned int Dlo = (unsigned int)D, Dhi = (unsigned int)(D >> 32);
            unsigned int Slo = (unsigned int)S, Shi = (unsigned int)(S >> 32);
            while (cand) {
                int a = __builtin_ctzll(cand);
                keepM |= (1ULL << a);
                unsigned long long Da = rdlane64(Dlo, Dhi, a);
                sacc |= rdlane64(Slo, Shi, a);
                cand &= ~(1ULL << a) & ~Da;
            }
            sacc_prev = sacc;
            if (lane == 0) ldsKeep = keepM;
            if (base + lane < N) keepSorted[base + lane] = (int)((keepM >> lane) & 1ULL);
            D = Dn; S = Sn;
        }
        __syncthreads();                       // barrier A
        unsigned long long keepM = ldsKeep;    // snapshot to register
        if (wid == 1 && w1ok) {                // publish word c+1 BEFORE new loads
            int wn = c + 1;
            if (2*lane == wn)          ldsInc = accx;
            else if (2*lane + 1 == wn) ldsInc = accy;
        }
        __syncthreads();                       // barrier B
        if (wid == 1 && w1ok) {
            // OR kept rows' full mask rows; stall here overlaps wave 0's next resolve
            unsigned long long kb = keepM;
            while (kb) {
                int a = __builtin_ctzll(kb); kb &= kb - 1ULL;
                ulonglong2 v = *(const ulonglong2*)(mask + (size_t)(base + a) * Wpad + 2*lane);
                accx |= v.x; accy |= v.y;
            }
        }
    }
}

// K5: write outputs in original order: boxes*m, score*m, float(cls*keep).
__global__ __launch_bounds__(256) void k_out(
    const float* __restrict__ boxes, const float* __restrict__ score,
    const int* __restrict__ cls, const int* __restrict__ rank,
    const int* __restrict__ keepSorted,
    float* __restrict__ out, int N)
{
    int n = blockIdx.x * blockDim.x + threadIdx.x;
    if (n >= N) return;
    int k = keepSorted[rank[n]];
    float m = (float)k;
    out[n*4+0] = boxes[n*4+0]*m;
    out[n*4+1] = boxes[n*4+1]*m;
    out[n*4+2] = boxes[n*4+2]*m;
    out[n*4+3] = boxes[n*4+3]*m;
    out[(long)N*4 + n] = score[n]*m;
    out[(long)N*5 + n] = (float)(cls[n] * k);
}

extern "C" void kernel_launch(void* const* d_in, const int* in_sizes, int n_in,
                              void* d_out, int out_size, void* d_ws, size_t ws_size,
                              hipStream_t stream) {
    const float* prop = (const float*)d_in[0];
    const float* reg  = (const float*)d_in[1];
    const float* clss = (const float*)d_in[2];
    const float* stds = (const float*)d_in[3];
    const int*   img  = (const int*)d_in[4];

    int N = in_sizes[0] / 4;
    int C = in_sizes[2] / N;
    int W = (N + 63) / 64;
    int Wpad = (W + 1) & ~1;          // even -> 16B rows

    char* ws = (char*)d_ws;
    size_t off = 0;
    float* boxes       = (float*)(ws + off); off += (size_t)N*4*sizeof(float);
    float* key         = (float*)(ws + off); off += (size_t)N*sizeof(float);
    float* score       = (float*)(ws + off); off += (size_t)N*sizeof(float);
    int*   cls         = (int*)  (ws + off); off += (size_t)N*sizeof(int);
    int*   rank        = (int*)  (ws + off); off += (size_t)N*sizeof(int);
    float* boxesSorted = (float*)(ws + off); off += (size_t)N*4*sizeof(float);
    float* areaSorted  = (float*)(ws + off); off += (size_t)N*sizeof(float);
    float* keySorted   = (float*)(ws + off); off += (size_t)N*sizeof(float);
    int*   keepSorted  = (int*)  (ws + off); off += (size_t)N*sizeof(int);
    int*   nValid      = (int*)  (ws + off); off += sizeof(int);
    off = (off + 15) & ~(size_t)15;   // 16B-align mask rows
    unsigned long long* mask  = (unsigned long long*)(ws + off);
    off += (size_t)N * Wpad * sizeof(unsigned long long);
    unsigned long long* diag  = (unsigned long long*)(ws + off);
    off += (size_t)N * sizeof(unsigned long long);
    unsigned long long* sdiag = (unsigned long long*)(ws + off);
    off += (size_t)N * sizeof(unsigned long long);
    (void)ws_size; (void)out_size; (void)n_in;

    int rowBlocks  = (N + 3) / 4;
    int thrBlocks  = (N + 255) / 256;
    int rankBlocks = (N + 63) / 64;

    k_decode<<<rowBlocks, 256, 0, stream>>>(prop, reg, clss, stds, img,
                                            boxes, key, score, cls, N, C);
    k_rank<<<rankBlocks, 256, (size_t)N*sizeof(float), stream>>>(key, boxes,
                                            boxesSorted, areaSorted, keySorted, rank, nValid, N);
    k_mask<<<rowBlocks, 256, 0, stream>>>(boxesSorted, areaSorted, keySorted,
                                          mask, diag, sdiag, N, W, Wpad);
    k_scan<<<1, 128, 0, stream>>>(mask, diag, sdiag, nValid, keepSorted, N, W, Wpad);
    k_out<<<thrBlocks, 256, 0, stream>>>(boxes, score, cls, rank, keepSorted,
                                         (float*)d_out, N);
}

// Round 6
// 228.642 us; speedup vs baseline: 2.3597x; 1.6687x over previous
//
#include <hip/hip_runtime.h>
#include <math.h>

#define NMS_THR 0.3f
#define NACC 7   // accumulator waves in k_scan (block = (1+NACC)*64 threads)

__device__ __forceinline__ float fmul(float a, float b){ return __fmul_rn(a,b); }
__device__ __forceinline__ float fadd(float a, float b){ return __fadd_rn(a,b); }
__device__ __forceinline__ float fsub(float a, float b){ return __fsub_rn(a,b); }

__device__ __forceinline__ unsigned long long rdlane64(unsigned int lo, unsigned int hi, int a) {
    unsigned long long l = (unsigned int)__builtin_amdgcn_readlane((int)lo, a);
    unsigned long long h = (unsigned int)__builtin_amdgcn_readlane((int)hi, a);
    return (h << 32) | l;
}

// K1: per-row softmax max/sum + argmax + per-class regression decode. One wave per row.
__global__ __launch_bounds__(256) void k_decode(
    const float* __restrict__ prop, const float* __restrict__ reg,
    const float* __restrict__ clss, const float* __restrict__ stds,
    const int* __restrict__ imgsz,
    float* __restrict__ boxes, float* __restrict__ key,
    float* __restrict__ score, int* __restrict__ cls,
    int N, int C)
{
    int wid  = threadIdx.x >> 6;
    int lane = threadIdx.x & 63;
    int n = blockIdx.x * 4 + wid;
    if (n >= N) return;
    const float* row = clss + (long)n * C;
    float ninf = -__builtin_inff();
    float x0 = (lane < C)      ? row[lane]      : ninf;
    float x1 = (lane + 64 < C) ? row[lane + 64] : ninf;
    float m = fmaxf(x0, x1);
    for (int o = 32; o > 0; o >>= 1) m = fmaxf(m, __shfl_xor(m, o));
    float e0 = (lane < C)      ? expf(x0 - m) : 0.0f;
    float e1 = (lane + 64 < C) ? expf(x1 - m) : 0.0f;
    float s = e0 + e1;
    for (int o = 32; o > 0; o >>= 1) s += __shfl_xor(s, o);
    float bv; int bi;
    if (e0 >= e1) { bv = e0; bi = lane; } else { bv = e1; bi = lane + 64; }
    for (int o = 32; o > 0; o >>= 1) {
        float ov = __shfl_xor(bv, o);
        int   oi = __shfl_xor(bi, o);
        if (ov > bv || (ov == bv && oi < bi)) { bv = ov; bi = oi; }
    }
    if (lane == 0) {
        float sc = 1.0f / s;
        int   c  = bi;
        int   valid = (c != 0);
        float p0 = prop[n*4+0], p1 = prop[n*4+1], p2 = prop[n*4+2], p3 = prop[n*4+3];
        float w  = fsub(p2, p0), h = fsub(p3, p1);
        float cx = fadd(p0, fmul(0.5f, w));
        float cy = fadd(p1, fmul(0.5f, h));
        const float* rr = reg + (long)n * C * 4 + (long)c * 4;
        float t0 = fmul(rr[0], stds[0]);
        float t1 = fmul(rr[1], stds[1]);
        float t2 = fmul(rr[2], stds[2]);
        float t3 = fmul(rr[3], stds[3]);
        float px = fadd(cx, fmul(w, t0));
        float py = fadd(cy, fmul(h, t1));
        float pw = fmul(w, expf(t2));
        float ph = fmul(h, expf(t3));
        float hi = (float)(imgsz[0] - 1);
        float bx1 = fminf(fmaxf(fsub(px, fmul(0.5f, pw)), 0.0f), hi);
        float by1 = fminf(fmaxf(fsub(py, fmul(0.5f, ph)), 0.0f), hi);
        float bx2 = fminf(fmaxf(fadd(px, fmul(0.5f, pw)), 0.0f), hi);
        float by2 = fminf(fmaxf(fadd(py, fmul(0.5f, ph)), 0.0f), hi);
        boxes[n*4+0]=bx1; boxes[n*4+1]=by1; boxes[n*4+2]=bx2; boxes[n*4+3]=by2;
        score[n] = sc;
        cls[n]   = c;
        key[n]   = valid ? sc : ninf;
    }
}

// K2: stable descending rank sort. 64 rows/block, 4 j-strips of 256 threads.
// Block 0 additionally computes nValid (count of keys != -inf).
__global__ __launch_bounds__(256) void k_rank(
    const float* __restrict__ key, const float* __restrict__ boxes,
    float* __restrict__ boxesSorted, float* __restrict__ areaSorted,
    float* __restrict__ keySorted, int* __restrict__ rank,
    int* __restrict__ nValidPtr, int N)
{
    extern __shared__ float lkey[];     // N floats
    __shared__ int part[256];
    int tid = threadIdx.x;
    for (int j = tid; j < N; j += 256) lkey[j] = key[j];
    __syncthreads();

    int i = blockIdx.x * 64 + (tid & 63);
    int s = tid >> 6;
    int Q = (N + 3) >> 2;
    int r_part = 0;
    if (i < N) {
        float ki = lkey[i];
        int j0 = s * Q, j1 = min(N, j0 + Q);
        for (int j = j0; j < j1; ++j) {
            float kj = lkey[j];
            r_part += (kj > ki) || (kj == ki && j < i);   // stable
        }
    }
    part[tid] = r_part;
    __syncthreads();

    if (tid < 64 && i < N) {
        int r = part[tid] + part[tid+64] + part[tid+128] + part[tid+192];
        float ki = lkey[i];
        rank[i] = r;
        float b0 = boxes[i*4+0], b1 = boxes[i*4+1], b2 = boxes[i*4+2], b3 = boxes[i*4+3];
        boxesSorted[r*4+0]=b0; boxesSorted[r*4+1]=b1; boxesSorted[r*4+2]=b2; boxesSorted[r*4+3]=b3;
        areaSorted[r] = fmul(fsub(b2,b0), fsub(b3,b1));
        keySorted[r]  = ki;
    }

    if (blockIdx.x == 0) {
        __syncthreads();
        float ninf = -__builtin_inff();
        int inv = 0;
        for (int j = tid; j < N; j += 256) inv += (lkey[j] == ninf);
        part[tid] = inv;
        __syncthreads();
        if (tid == 0) {
            int t = 0;
            for (int q = 0; q < 256; ++q) t += part[q];
            nValidPtr[0] = N - t;
        }
    }
}

// K3: suppression bitmask, ROW-MAJOR padded: mask[i*Wpad + w]; rows 16B-aligned.
// diag[i] = word i>>6 of row i; sdiag[i] = word (i>>6)+1 (0 if out of range).
__global__ __launch_bounds__(256) void k_mask(
    const float* __restrict__ bs, const float* __restrict__ areas,
    const float* __restrict__ keySorted, unsigned long long* __restrict__ mask,
    unsigned long long* __restrict__ diag, unsigned long long* __restrict__ sdiag,
    int N, int W, int Wpad)
{
    int wid  = threadIdx.x >> 6;
    int lane = threadIdx.x & 63;
    int i = blockIdx.x * 4 + wid;
    if (i >= N) return;
    if (keySorted[i] == -__builtin_inff()) return;   // invalid row: never read
    float ax1 = bs[i*4+0], ay1 = bs[i*4+1], ax2 = bs[i*4+2], ay2 = bs[i*4+3];
    float aa  = areas[i];
    int w0 = i >> 6;
    if (lane == 0 && w0 + 1 >= W) sdiag[i] = 0ULL;
    for (int w = w0; w < W; ++w) {
        int j = w*64 + lane;
        int bit = 0;
        if (j < N && j > i) {
            float bx1 = bs[j*4+0], by1 = bs[j*4+1], bx2 = bs[j*4+2], by2 = bs[j*4+3];
            float ba  = areas[j];
            float ix1 = fmaxf(ax1,bx1), iy1 = fmaxf(ay1,by1);
            float ix2 = fminf(ax2,bx2), iy2 = fminf(ay2,by2);
            float iw = fmaxf(fsub(ix2,ix1), 0.0f);
            float ih = fmaxf(fsub(iy2,iy1), 0.0f);
            float inter = fmul(iw, ih);
            float denom = fadd(fsub(fadd(aa, ba), inter), 1e-9f);
            float iou = inter / denom;
            bit = (iou > NMS_THR) ? 1 : 0;
        }
        unsigned long long bm = __ballot(bit);
        if (lane == 0) {
            mask[(long)i*Wpad + w] = bm;
            if (w == w0)     diag[i]  = bm;
            if (w == w0 + 1) sdiag[i] = bm;
        }
    }
}

// K4: wave-specialized chunked greedy scan. One block, 1 resolver wave + NACC
// accumulator waves. Resolver: scalar ctz+readlane chain over diag; sacc =
// OR of sdiag over kept rows (word c+1 of chunk c). Accumulators: kept rows
// dealt round-robin by keep-order position; each wave loads up to 4 rows into
// NAMED ulonglong2 regs (independent, one vmcnt wait) and ORs into its
// partial (lane L owns words 2L,2L+1). Word c+1 published to ldsPart[1..NACC]
// between barriers A and B, BEFORE issuing chunk-c loads -> inc never waits
// on in-flight memory. inc_c = OR(ldsPart) | sacc_prev.
__global__ __launch_bounds__((NACC+1)*64, 1) void k_scan(
    const unsigned long long* __restrict__ mask,
    const unsigned long long* __restrict__ diag,
    const unsigned long long* __restrict__ sdiag,
    const int* __restrict__ nValidPtr,
    int* __restrict__ keepSorted, int N, int W, int Wpad)
{
    __shared__ unsigned long long ldsPart[NACC+1];
    __shared__ unsigned long long ldsKeep;
    int tid  = threadIdx.x;
    int wid  = tid >> 6;
    int lane = tid & 63;
    for (int i = tid; i < N; i += (NACC+1)*64) keepSorted[i] = 0;
    if (tid <= NACC) ldsPart[tid] = 0ULL;
    if (tid == 0) ldsKeep = 0ULL;
    __syncthreads();

    int nValid  = nValidPtr[0];
    int nChunks = (nValid + 63) >> 6;

    // resolver state
    unsigned long long D = 0ULL, S = 0ULL, sacc_prev = 0ULL;
    if (wid == 0 && lane < nValid) { D = diag[lane]; S = sdiag[lane]; }
    // accumulator state: lane L owns words 2L, 2L+1
    unsigned long long accx = 0ULL, accy = 0ULL;
    bool accWave = (wid >= 1);
    int  accIdx  = wid - 1;                  // 0..NACC-1
    bool laneok  = (2*lane + 1 < Wpad);      // full ulonglong2 in row bounds

    for (int c = 0; c < nChunks; ++c) {
        int base = c << 6;
        if (wid == 0) {
            // prefetch next chunk's diag/sdiag (one chunk of slack)
            unsigned long long Dn = 0ULL, Sn = 0ULL;
            int nr = base + 64 + lane;
            if (c + 1 < nChunks && nr < nValid) { Dn = diag[nr]; Sn = sdiag[nr]; }

            unsigned long long inc = sacc_prev;
#pragma unroll
            for (int k = 1; k <= NACC; ++k) inc |= ldsPart[k];
            int nv = nValid - base;
            unsigned long long validBits = (nv >= 64) ? ~0ULL : ((1ULL << nv) - 1ULL);
            unsigned long long cand = validBits & ~inc;
            unsigned long long keepM = 0ULL, sacc = 0ULL;
            unsigned int Dlo = (unsigned int)D, Dhi = (unsigned int)(D >> 32);
            unsigned int Slo = (unsigned int)S, Shi = (unsigned int)(S >> 32);
            while (cand) {
                int a = __builtin_ctzll(cand);
                keepM |= (1ULL << a);
                unsigned long long Da = rdlane64(Dlo, Dhi, a);
                sacc |= rdlane64(Slo, Shi, a);
                cand &= ~(1ULL << a) & ~Da;
            }
            sacc_prev = sacc;
            if (lane == 0) ldsKeep = keepM;
            if (base + lane < N) keepSorted[base + lane] = (int)((keepM >> lane) & 1ULL);
            D = Dn; S = Sn;
        }
        __syncthreads();                       // barrier A
        unsigned long long keepM = ldsKeep;    // snapshot
        int wn = c + 1;
        if (accWave && laneok) {               // publish word c+1 BEFORE new loads
            if (2*lane == wn)          ldsPart[wid] = accx;
            else if (2*lane + 1 == wn) ldsPart[wid] = accy;
        }
        __syncthreads();                       // barrier B
        if (accWave && laneok && keepM) {
            // deal kept rows round-robin; this wave takes positions = accIdx mod NACC
            int r0_ = -1, r1_ = -1, r2_ = -1, r3_ = -1;
            unsigned long long kbExtra = 0ULL;
            {
                unsigned long long kb = keepM;
                int cnt = 0;
                while (kb) {
                    int a = __builtin_ctzll(kb); kb &= kb - 1ULL;
                    if (cnt % NACC == accIdx) {
                        int q = cnt / NACC;
                        if      (q == 0) r0_ = a;
                        else if (q == 1) r1_ = a;
                        else if (q == 2) r2_ = a;
                        else if (q == 3) r3_ = a;
                        else kbExtra |= 1ULL << a;
                    }
                    ++cnt;
                }
            }
            ulonglong2 v0 = {0,0}, v1 = {0,0}, v2 = {0,0}, v3 = {0,0};
            if (r0_ >= 0) v0 = *(const ulonglong2*)(mask + (size_t)(base + r0_) * Wpad + 2*lane);
            if (r1_ >= 0) v1 = *(const ulonglong2*)(mask + (size_t)(base + r1_) * Wpad + 2*lane);
            if (r2_ >= 0) v2 = *(const ulonglong2*)(mask + (size_t)(base + r2_) * Wpad + 2*lane);
            if (r3_ >= 0) v3 = *(const ulonglong2*)(mask + (size_t)(base + r3_) * Wpad + 2*lane);
            accx |= (v0.x | v1.x) | (v2.x | v3.x);
            accy |= (v0.y | v1.y) | (v2.y | v3.y);
            while (kbExtra) {                  // >4*NACC kept in one chunk (rare)
                int a = __builtin_ctzll(kbExtra); kbExtra &= kbExtra - 1ULL;
                ulonglong2 v = *(const ulonglong2*)(mask + (size_t)(base + a) * Wpad + 2*lane);
                accx |= v.x; accy |= v.y;
            }
        }
    }
}

// K5: write outputs in original order: boxes*m, score*m, float(cls*keep).
__global__ __launch_bounds__(256) void k_out(
    const float* __restrict__ boxes, const float* __restrict__ score,
    const int* __restrict__ cls, const int* __restrict__ rank,
    const int* __restrict__ keepSorted,
    float* __restrict__ out, int N)
{
    int n = blockIdx.x * blockDim.x + threadIdx.x;
    if (n >= N) return;
    int k = keepSorted[rank[n]];
    float m = (float)k;
    out[n*4+0] = boxes[n*4+0]*m;
    out[n*4+1] = boxes[n*4+1]*m;
    out[n*4+2] = boxes[n*4+2]*m;
    out[n*4+3] = boxes[n*4+3]*m;
    out[(long)N*4 + n] = score[n]*m;
    out[(long)N*5 + n] = (float)(cls[n] * k);
}

extern "C" void kernel_launch(void* const* d_in, const int* in_sizes, int n_in,
                              void* d_out, int out_size, void* d_ws, size_t ws_size,
                              hipStream_t stream) {
    const float* prop = (const float*)d_in[0];
    const float* reg  = (const float*)d_in[1];
    const float* clss = (const float*)d_in[2];
    const float* stds = (const float*)d_in[3];
    const int*   img  = (const int*)d_in[4];

    int N = in_sizes[0] / 4;
    int C = in_sizes[2] / N;
    int W = (N + 63) / 64;
    int Wpad = (W + 1) & ~1;          // even -> 16B rows

    char* ws = (char*)d_ws;
    size_t off = 0;
    float* boxes       = (float*)(ws + off); off += (size_t)N*4*sizeof(float);
    float* key         = (float*)(ws + off); off += (size_t)N*sizeof(float);
    float* score       = (float*)(ws + off); off += (size_t)N*sizeof(float);
    int*   cls         = (int*)  (ws + off); off += (size_t)N*sizeof(int);
    int*   rank        = (int*)  (ws + off); off += (size_t)N*sizeof(int);
    float* boxesSorted = (float*)(ws + off); off += (size_t)N*4*sizeof(float);
    float* areaSorted  = (float*)(ws + off); off += (size_t)N*sizeof(float);
    float* keySorted   = (float*)(ws + off); off += (size_t)N*sizeof(float);
    int*   keepSorted  = (int*)  (ws + off); off += (size_t)N*sizeof(int);
    int*   nValid      = (int*)  (ws + off); off += sizeof(int);
    off = (off + 15) & ~(size_t)15;   // 16B-align mask rows
    unsigned long long* mask  = (unsigned long long*)(ws + off);
    off += (size_t)N * Wpad * sizeof(unsigned long long);
    unsigned long long* diag  = (unsigned long long*)(ws + off);
    off += (size_t)N * sizeof(unsigned long long);
    unsigned long long* sdiag = (unsigned long long*)(ws + off);
    off += (size_t)N * sizeof(unsigned long long);
    (void)ws_size; (void)out_size; (void)n_in;

    int rowBlocks  = (N + 3) / 4;
    int thrBlocks  = (N + 255) / 256;
    int rankBlocks = (N + 63) / 64;

    k_decode<<<rowBlocks, 256, 0, stream>>>(prop, reg, clss, stds, img,
                                            boxes, key, score, cls, N, C);
    k_rank<<<rankBlocks, 256, (size_t)N*sizeof(float), stream>>>(key, boxes,
                                            boxesSorted, areaSorted, keySorted, rank, nValid, N);
    k_mask<<<rowBlocks, 256, 0, stream>>>(boxesSorted, areaSorted, keySorted,
                                          mask, diag, sdiag, N, W, Wpad);
    k_scan<<<1, (NACC+1)*64, 0, stream>>>(mask, diag, sdiag, nValid, keepSorted, N, W, Wpad);
    k_out<<<thrBlocks, 256, 0, stream>>>(boxes, score, cls, rank, keepSorted,
                                         (float*)d_out, N);
}

// Round 7
// 219.767 us; speedup vs baseline: 2.4550x; 1.0404x over previous
//
#include <hip/hip_runtime.h>
#include <math.h>

#define NMS_THR 0.3f
#define NACC 8   // accumulator waves in k_scan (block = (1+NACC)*64 threads)

__device__ __forceinline__ float fmul(float a, float b){ return __fmul_rn(a,b); }
__device__ __forceinline__ float fadd(float a, float b){ return __fadd_rn(a,b); }
__device__ __forceinline__ float fsub(float a, float b){ return __fsub_rn(a,b); }

// Raw barrier: LDS ordering only — does NOT drain vmcnt, so prefetches and
// row loads stay in flight across it (unlike __syncthreads).
#define BAR_LDS() asm volatile("s_waitcnt lgkmcnt(0)\n\ts_barrier" ::: "memory")

__device__ __forceinline__ unsigned long long rdlane64(unsigned int lo, unsigned int hi, int a) {
    unsigned long long l = (unsigned int)__builtin_amdgcn_readlane((int)lo, a);
    unsigned long long h = (unsigned int)__builtin_amdgcn_readlane((int)hi, a);
    return (h << 32) | l;
}

// K1: per-row softmax max/sum + argmax + per-class regression decode. One wave per row.
__global__ __launch_bounds__(256) void k_decode(
    const float* __restrict__ prop, const float* __restrict__ reg,
    const float* __restrict__ clss, const float* __restrict__ stds,
    const int* __restrict__ imgsz,
    float* __restrict__ boxes, float* __restrict__ key,
    float* __restrict__ score, int* __restrict__ cls,
    int N, int C)
{
    int wid  = threadIdx.x >> 6;
    int lane = threadIdx.x & 63;
    int n = blockIdx.x * 4 + wid;
    if (n >= N) return;
    const float* row = clss + (long)n * C;
    float ninf = -__builtin_inff();
    float x0 = (lane < C)      ? row[lane]      : ninf;
    float x1 = (lane + 64 < C) ? row[lane + 64] : ninf;
    float m = fmaxf(x0, x1);
    for (int o = 32; o > 0; o >>= 1) m = fmaxf(m, __shfl_xor(m, o));
    float e0 = (lane < C)      ? expf(x0 - m) : 0.0f;
    float e1 = (lane + 64 < C) ? expf(x1 - m) : 0.0f;
    float s = e0 + e1;
    for (int o = 32; o > 0; o >>= 1) s += __shfl_xor(s, o);
    float bv; int bi;
    if (e0 >= e1) { bv = e0; bi = lane; } else { bv = e1; bi = lane + 64; }
    for (int o = 32; o > 0; o >>= 1) {
        float ov = __shfl_xor(bv, o);
        int   oi = __shfl_xor(bi, o);
        if (ov > bv || (ov == bv && oi < bi)) { bv = ov; bi = oi; }
    }
    if (lane == 0) {
        float sc = 1.0f / s;
        int   c  = bi;
        int   valid = (c != 0);
        float p0 = prop[n*4+0], p1 = prop[n*4+1], p2 = prop[n*4+2], p3 = prop[n*4+3];
        float w  = fsub(p2, p0), h = fsub(p3, p1);
        float cx = fadd(p0, fmul(0.5f, w));
        float cy = fadd(p1, fmul(0.5f, h));
        const float* rr = reg + (long)n * C * 4 + (long)c * 4;
        float t0 = fmul(rr[0], stds[0]);
        float t1 = fmul(rr[1], stds[1]);
        float t2 = fmul(rr[2], stds[2]);
        float t3 = fmul(rr[3], stds[3]);
        float px = fadd(cx, fmul(w, t0));
        float py = fadd(cy, fmul(h, t1));
        float pw = fmul(w, expf(t2));
        float ph = fmul(h, expf(t3));
        float hi = (float)(imgsz[0] - 1);
        float bx1 = fminf(fmaxf(fsub(px, fmul(0.5f, pw)), 0.0f), hi);
        float by1 = fminf(fmaxf(fsub(py, fmul(0.5f, ph)), 0.0f), hi);
        float bx2 = fminf(fmaxf(fadd(px, fmul(0.5f, pw)), 0.0f), hi);
        float by2 = fminf(fmaxf(fadd(py, fmul(0.5f, ph)), 0.0f), hi);
        boxes[n*4+0]=bx1; boxes[n*4+1]=by1; boxes[n*4+2]=bx2; boxes[n*4+3]=by2;
        score[n] = sc;
        cls[n]   = c;
        key[n]   = valid ? sc : ninf;
    }
}

// K2: stable descending rank sort. 64 rows/block, 4 j-strips of 256 threads.
// Block 0 additionally computes nValid (count of keys != -inf).
__global__ __launch_bounds__(256) void k_rank(
    const float* __restrict__ key, const float* __restrict__ boxes,
    float* __restrict__ boxesSorted, float* __restrict__ areaSorted,
    float* __restrict__ keySorted, int* __restrict__ rank,
    int* __restrict__ nValidPtr, int N)
{
    extern __shared__ float lkey[];     // N floats
    __shared__ int part[256];
    int tid = threadIdx.x;
    for (int j = tid; j < N; j += 256) lkey[j] = key[j];
    __syncthreads();

    int i = blockIdx.x * 64 + (tid & 63);
    int s = tid >> 6;
    int Q = (N + 3) >> 2;
    int r_part = 0;
    if (i < N) {
        float ki = lkey[i];
        int j0 = s * Q, j1 = min(N, j0 + Q);
        for (int j = j0; j < j1; ++j) {
            float kj = lkey[j];
            r_part += (kj > ki) || (kj == ki && j < i);   // stable
        }
    }
    part[tid] = r_part;
    __syncthreads();

    if (tid < 64 && i < N) {
        int r = part[tid] + part[tid+64] + part[tid+128] + part[tid+192];
        float ki = lkey[i];
        rank[i] = r;
        float b0 = boxes[i*4+0], b1 = boxes[i*4+1], b2 = boxes[i*4+2], b3 = boxes[i*4+3];
        boxesSorted[r*4+0]=b0; boxesSorted[r*4+1]=b1; boxesSorted[r*4+2]=b2; boxesSorted[r*4+3]=b3;
        areaSorted[r] = fmul(fsub(b2,b0), fsub(b3,b1));
        keySorted[r]  = ki;
    }

    if (blockIdx.x == 0) {
        __syncthreads();
        float ninf = -__builtin_inff();
        int inv = 0;
        for (int j = tid; j < N; j += 256) inv += (lkey[j] == ninf);
        part[tid] = inv;
        __syncthreads();
        if (tid == 0) {
            int t = 0;
            for (int q = 0; q < 256; ++q) t += part[q];
            nValidPtr[0] = N - t;
        }
    }
}

// K3: suppression bitmask, ROW-MAJOR padded: mask[i*Wpad + w]; rows 16B-aligned.
// diag[i] = word i>>6 of row i; sdiag[i] = word (i>>6)+1 (0 if out of range).
__global__ __launch_bounds__(256) void k_mask(
    const float* __restrict__ bs, const float* __restrict__ areas,
    const float* __restrict__ keySorted, unsigned long long* __restrict__ mask,
    unsigned long long* __restrict__ diag, unsigned long long* __restrict__ sdiag,
    int N, int W, int Wpad)
{
    int wid  = threadIdx.x >> 6;
    int lane = threadIdx.x & 63;
    int i = blockIdx.x * 4 + wid;
    if (i >= N) return;
    if (keySorted[i] == -__builtin_inff()) return;   // invalid row: never read
    float ax1 = bs[i*4+0], ay1 = bs[i*4+1], ax2 = bs[i*4+2], ay2 = bs[i*4+3];
    float aa  = areas[i];
    int w0 = i >> 6;
    if (lane == 0 && w0 + 1 >= W) sdiag[i] = 0ULL;
    for (int w = w0; w < W; ++w) {
        int j = w*64 + lane;
        int bit = 0;
        if (j < N && j > i) {
            float bx1 = bs[j*4+0], by1 = bs[j*4+1], bx2 = bs[j*4+2], by2 = bs[j*4+3];
            float ba  = areas[j];
            float ix1 = fmaxf(ax1,bx1), iy1 = fmaxf(ay1,by1);
            float ix2 = fminf(ax2,bx2), iy2 = fminf(ay2,by2);
            float iw = fmaxf(fsub(ix2,ix1), 0.0f);
            float ih = fmaxf(fsub(iy2,iy1), 0.0f);
            float inter = fmul(iw, ih);
            float denom = fadd(fsub(fadd(aa, ba), inter), 1e-9f);
            float iou = inter / denom;
            bit = (iou > NMS_THR) ? 1 : 0;
        }
        unsigned long long bm = __ballot(bit);
        if (lane == 0) {
            mask[(long)i*Wpad + w] = bm;
            if (w == w0)     diag[i]  = bm;
            if (w == w0 + 1) sdiag[i] = bm;
        }
    }
}

// K4: wave-specialized chunked greedy scan. One block, 1 resolver wave + NACC
// accumulator waves. Raw lgkmcnt-only barriers (vmem stays in flight).
// Resolver: scalar ctz+readlane chain over diag; sacc = OR of sdiag over kept
// rows (word c+1 of chunk c). Accumulators: wave k owns kept bits [8k,8k+8);
// each loads its rows' ulonglong2 (lane L owns words 2L,2L+1) and ORs into a
// partial. Word c+1 published to ldsPart[1..NACC] between barriers A and B,
// BEFORE issuing chunk-c loads. inc_c = OR(ldsPart) | sacc_prev.
__global__ __launch_bounds__((NACC+1)*64, 1) void k_scan(
    const unsigned long long* __restrict__ mask,
    const unsigned long long* __restrict__ diag,
    const unsigned long long* __restrict__ sdiag,
    const int* __restrict__ nValidPtr,
    int* __restrict__ keepSorted, int N, int W, int Wpad)
{
    __shared__ unsigned long long ldsPart[NACC+1];
    __shared__ unsigned long long ldsKeep;
    int tid  = threadIdx.x;
    int wid  = tid >> 6;
    int lane = tid & 63;
    for (int i = tid; i < N; i += (NACC+1)*64) keepSorted[i] = 0;
    if (tid <= NACC) ldsPart[tid] = 0ULL;
    if (tid == 0) ldsKeep = 0ULL;
    __syncthreads();

    int nValid  = nValidPtr[0];
    int nChunks = (nValid + 63) >> 6;

    // resolver state
    unsigned long long D = 0ULL, S = 0ULL, sacc_prev = 0ULL;
    if (wid == 0 && lane < nValid) { D = diag[lane]; S = sdiag[lane]; }
    // accumulator state: lane L owns words 2L, 2L+1
    unsigned long long accx = 0ULL, accy = 0ULL;
    bool accWave = (wid >= 1);
    int  accIdx  = wid - 1;                  // 0..NACC-1
    bool laneok  = (2*lane + 1 < Wpad);      // full ulonglong2 in row bounds

    for (int c = 0; c < nChunks; ++c) {
        int base = c << 6;
        if (wid == 0) {
            // prefetch next chunk's diag/sdiag (vmem, never drained by BAR_LDS)
            unsigned long long Dn = 0ULL, Sn = 0ULL;
            int nr = base + 64 + lane;
            if (c + 1 < nChunks && nr < nValid) { Dn = diag[nr]; Sn = sdiag[nr]; }

            unsigned long long inc = sacc_prev;
#pragma unroll
            for (int k = 1; k <= NACC; ++k) inc |= ldsPart[k];
            int nv = nValid - base;
            unsigned long long validBits = (nv >= 64) ? ~0ULL : ((1ULL << nv) - 1ULL);
            unsigned long long cand = validBits & ~inc;
            unsigned long long keepM = 0ULL, sacc = 0ULL;
            unsigned int Dlo = (unsigned int)D, Dhi = (unsigned int)(D >> 32);
            unsigned int Slo = (unsigned int)S, Shi = (unsigned int)(S >> 32);
            while (cand) {
                int a = __builtin_ctzll(cand);
                keepM |= (1ULL << a);
                unsigned long long Da = rdlane64(Dlo, Dhi, a);
                sacc |= rdlane64(Slo, Shi, a);
                cand &= ~(1ULL << a) & ~Da;
            }
            sacc_prev = sacc;
            if (lane == 0) ldsKeep = keepM;
            if (base + lane < N) keepSorted[base + lane] = (int)((keepM >> lane) & 1ULL);
            D = Dn; S = Sn;
        }
        BAR_LDS();                             // barrier A (LDS-order only)
        unsigned long long keepM = ldsKeep;    // broadcast snapshot
        int wn = c + 1;
        if (accWave && laneok) {               // publish word c+1 BEFORE new loads
            if (2*lane == wn)          ldsPart[wid] = accx;
            else if (2*lane + 1 == wn) ldsPart[wid] = accy;
        }
        BAR_LDS();                             // barrier B
        if (accWave && laneok) {
            // byte-slice deal: this wave owns kept bits [8*accIdx, 8*accIdx+8)
            unsigned int myb = (unsigned int)((keepM >> (accIdx * 8)) & 0xFFULL);
            if (myb) {
                const unsigned long long* mb = mask + (size_t)base * Wpad + 2*lane;
                int a0, a1 = -1, a2 = -1, a3 = -1;
                unsigned int b = myb;
                a0 = __builtin_ctz(b) + accIdx*8; b &= b - 1;
                if (b) { a1 = __builtin_ctz(b) + accIdx*8; b &= b - 1; }
                if (b) { a2 = __builtin_ctz(b) + accIdx*8; b &= b - 1; }
                if (b) { a3 = __builtin_ctz(b) + accIdx*8; b &= b - 1; }
                ulonglong2 v0 = {0,0}, v1 = {0,0}, v2 = {0,0}, v3 = {0,0};
                v0 = *(const ulonglong2*)(mb + (size_t)a0 * Wpad);
                if (a1 >= 0) v1 = *(const ulonglong2*)(mb + (size_t)a1 * Wpad);
                if (a2 >= 0) v2 = *(const ulonglong2*)(mb + (size_t)a2 * Wpad);
                if (a3 >= 0) v3 = *(const ulonglong2*)(mb + (size_t)a3 * Wpad);
                accx |= (v0.x | v1.x) | (v2.x | v3.x);
                accy |= (v0.y | v1.y) | (v2.y | v3.y);
                while (b) {                    // >4 kept in this byte (rare)
                    int a = __builtin_ctz(b) + accIdx*8; b &= b - 1;
                    ulonglong2 v = *(const ulonglong2*)(mb + (size_t)a * Wpad);
                    accx |= v.x; accy |= v.y;
                }
            }
        }
    }
}

// K5: write outputs in original order: boxes*m, score*m, float(cls*keep).
__global__ __launch_bounds__(256) void k_out(
    const float* __restrict__ boxes, const float* __restrict__ score,
    const int* __restrict__ cls, const int* __restrict__ rank,
    const int* __restrict__ keepSorted,
    float* __restrict__ out, int N)
{
    int n = blockIdx.x * blockDim.x + threadIdx.x;
    if (n >= N) return;
    int k = keepSorted[rank[n]];
    float m = (float)k;
    out[n*4+0] = boxes[n*4+0]*m;
    out[n*4+1] = boxes[n*4+1]*m;
    out[n*4+2] = boxes[n*4+2]*m;
    out[n*4+3] = boxes[n*4+3]*m;
    out[(long)N*4 + n] = score[n]*m;
    out[(long)N*5 + n] = (float)(cls[n] * k);
}

extern "C" void kernel_launch(void* const* d_in, const int* in_sizes, int n_in,
                              void* d_out, int out_size, void* d_ws, size_t ws_size,
                              hipStream_t stream) {
    const float* prop = (const float*)d_in[0];
    const float* reg  = (const float*)d_in[1];
    const float* clss = (const float*)d_in[2];
    const float* stds = (const float*)d_in[3];
    const int*   img  = (const int*)d_in[4];

    int N = in_sizes[0] / 4;
    int C = in_sizes[2] / N;
    int W = (N + 63) / 64;
    int Wpad = (W + 1) & ~1;          // even -> 16B rows

    char* ws = (char*)d_ws;
    size_t off = 0;
    float* boxes       = (float*)(ws + off); off += (size_t)N*4*sizeof(float);
    float* key         = (float*)(ws + off); off += (size_t)N*sizeof(float);
    float* score       = (float*)(ws + off); off += (size_t)N*sizeof(float);
    int*   cls         = (int*)  (ws + off); off += (size_t)N*sizeof(int);
    int*   rank        = (int*)  (ws + off); off += (size_t)N*sizeof(int);
    float* boxesSorted = (float*)(ws + off); off += (size_t)N*4*sizeof(float);
    float* areaSorted  = (float*)(ws + off); off += (size_t)N*sizeof(float);
    float* keySorted   = (float*)(ws + off); off += (size_t)N*sizeof(float);
    int*   keepSorted  = (int*)  (ws + off); off += (size_t)N*sizeof(int);
    int*   nValid      = (int*)  (ws + off); off += sizeof(int);
    off = (off + 15) & ~(size_t)15;   // 16B-align mask rows
    unsigned long long* mask  = (unsigned long long*)(ws + off);
    off += (size_t)N * Wpad * sizeof(unsigned long long);
    unsigned long long* diag  = (unsigned long long*)(ws + off);
    off += (size_t)N * sizeof(unsigned long long);
    unsigned long long* sdiag = (unsigned long long*)(ws + off);
    off += (size_t)N * sizeof(unsigned long long);
    (void)ws_size; (void)out_size; (void)n_in;

    int rowBlocks  = (N + 3) / 4;
    int thrBlocks  = (N + 255) / 256;
    int rankBlocks = (N + 63) / 64;

    k_decode<<<rowBlocks, 256, 0, stream>>>(prop, reg, clss, stds, img,
                                            boxes, key, score, cls, N, C);
    k_rank<<<rankBlocks, 256, (size_t)N*sizeof(float), stream>>>(key, boxes,
                                            boxesSorted, areaSorted, keySorted, rank, nValid, N);
    k_mask<<<rowBlocks, 256, 0, stream>>>(boxesSorted, areaSorted, keySorted,
                                          mask, diag, sdiag, N, W, Wpad);
    k_scan<<<1, (NACC+1)*64, 0, stream>>>(mask, diag, sdiag, nValid, keepSorted, N, W, Wpad);
    k_out<<<thrBlocks, 256, 0, stream>>>(boxes, score, cls, rank, keepSorted,
                                         (float*)d_out, N);
}

// Round 8
// 184.651 us; speedup vs baseline: 2.9219x; 1.1902x over previous
//
#include <hip/hip_runtime.h>
#include <math.h>

#define NMS_THR 0.3f
#define NACC 8   // accumulator waves in k_scan (block = (1+NACC)*64 threads)

__device__ __forceinline__ float fmul(float a, float b){ return __fmul_rn(a,b); }
__device__ __forceinline__ float fadd(float a, float b){ return __fadd_rn(a,b); }
__device__ __forceinline__ float fsub(float a, float b){ return __fsub_rn(a,b); }

// Raw barrier: LDS ordering only — does NOT drain vmcnt, so prefetches and
// row loads stay in flight across it (unlike __syncthreads).
#define BAR_LDS() asm volatile("s_waitcnt lgkmcnt(0)\n\ts_barrier" ::: "memory")

__device__ __forceinline__ unsigned long long rdlane64(unsigned long long v, int a) {
    unsigned long long l = (unsigned int)__builtin_amdgcn_readlane((int)(unsigned int)v, a);
    unsigned long long h = (unsigned int)__builtin_amdgcn_readlane((int)(unsigned int)(v >> 32), a);
    return (h << 32) | l;
}
__device__ __forceinline__ unsigned long long rfl64(unsigned long long x){
    unsigned int lo = (unsigned int)__builtin_amdgcn_readfirstlane((int)(unsigned int)x);
    unsigned int hi = (unsigned int)__builtin_amdgcn_readfirstlane((int)(unsigned int)(x >> 32));
    return ((unsigned long long)hi << 32) | lo;
}

// K1: per-row softmax max/sum + argmax + per-class regression decode. One wave per row.
__global__ __launch_bounds__(256) void k_decode(
    const float* __restrict__ prop, const float* __restrict__ reg,
    const float* __restrict__ clss, const float* __restrict__ stds,
    const int* __restrict__ imgsz,
    float* __restrict__ boxes, float* __restrict__ key,
    float* __restrict__ score, int* __restrict__ cls,
    int N, int C)
{
    int wid  = threadIdx.x >> 6;
    int lane = threadIdx.x & 63;
    int n = blockIdx.x * 4 + wid;
    if (n >= N) return;
    const float* row = clss + (long)n * C;
    float ninf = -__builtin_inff();
    float x0 = (lane < C)      ? row[lane]      : ninf;
    float x1 = (lane + 64 < C) ? row[lane + 64] : ninf;
    float m = fmaxf(x0, x1);
    for (int o = 32; o > 0; o >>= 1) m = fmaxf(m, __shfl_xor(m, o));
    float e0 = (lane < C)      ? expf(x0 - m) : 0.0f;
    float e1 = (lane + 64 < C) ? expf(x1 - m) : 0.0f;
    float s = e0 + e1;
    for (int o = 32; o > 0; o >>= 1) s += __shfl_xor(s, o);
    float bv; int bi;
    if (e0 >= e1) { bv = e0; bi = lane; } else { bv = e1; bi = lane + 64; }
    for (int o = 32; o > 0; o >>= 1) {
        float ov = __shfl_xor(bv, o);
        int   oi = __shfl_xor(bi, o);
        if (ov > bv || (ov == bv && oi < bi)) { bv = ov; bi = oi; }
    }
    if (lane == 0) {
        float sc = 1.0f / s;
        int   c  = bi;
        int   valid = (c != 0);
        float p0 = prop[n*4+0], p1 = prop[n*4+1], p2 = prop[n*4+2], p3 = prop[n*4+3];
        float w  = fsub(p2, p0), h = fsub(p3, p1);
        float cx = fadd(p0, fmul(0.5f, w));
        float cy = fadd(p1, fmul(0.5f, h));
        const float* rr = reg + (long)n * C * 4 + (long)c * 4;
        float t0 = fmul(rr[0], stds[0]);
        float t1 = fmul(rr[1], stds[1]);
        float t2 = fmul(rr[2], stds[2]);
        float t3 = fmul(rr[3], stds[3]);
        float px = fadd(cx, fmul(w, t0));
        float py = fadd(cy, fmul(h, t1));
        float pw = fmul(w, expf(t2));
        float ph = fmul(h, expf(t3));
        float hi = (float)(imgsz[0] - 1);
        float bx1 = fminf(fmaxf(fsub(px, fmul(0.5f, pw)), 0.0f), hi);
        float by1 = fminf(fmaxf(fsub(py, fmul(0.5f, ph)), 0.0f), hi);
        float bx2 = fminf(fmaxf(fadd(px, fmul(0.5f, pw)), 0.0f), hi);
        float by2 = fminf(fmaxf(fadd(py, fmul(0.5f, ph)), 0.0f), hi);
        boxes[n*4+0]=bx1; boxes[n*4+1]=by1; boxes[n*4+2]=bx2; boxes[n*4+3]=by2;
        score[n] = sc;
        cls[n]   = c;
        key[n]   = valid ? sc : ninf;
    }
}

// K2: stable descending rank sort. 64 rows/block, 4 j-strips of 256 threads.
// Block 0 additionally computes nValid (count of keys != -inf).
__global__ __launch_bounds__(256) void k_rank(
    const float* __restrict__ key, const float* __restrict__ boxes,
    float* __restrict__ boxesSorted, float* __restrict__ areaSorted,
    float* __restrict__ keySorted, int* __restrict__ rank,
    int* __restrict__ nValidPtr, int N)
{
    extern __shared__ float lkey[];     // N floats
    __shared__ int part[256];
    int tid = threadIdx.x;
    for (int j = tid; j < N; j += 256) lkey[j] = key[j];
    __syncthreads();

    int i = blockIdx.x * 64 + (tid & 63);
    int s = tid >> 6;
    int Q = (N + 3) >> 2;
    int r_part = 0;
    if (i < N) {
        float ki = lkey[i];
        int j0 = s * Q, j1 = min(N, j0 + Q);
        for (int j = j0; j < j1; ++j) {
            float kj = lkey[j];
            r_part += (kj > ki) || (kj == ki && j < i);   // stable
        }
    }
    part[tid] = r_part;
    __syncthreads();

    if (tid < 64 && i < N) {
        int r = part[tid] + part[tid+64] + part[tid+128] + part[tid+192];
        float ki = lkey[i];
        rank[i] = r;
        float b0 = boxes[i*4+0], b1 = boxes[i*4+1], b2 = boxes[i*4+2], b3 = boxes[i*4+3];
        boxesSorted[r*4+0]=b0; boxesSorted[r*4+1]=b1; boxesSorted[r*4+2]=b2; boxesSorted[r*4+3]=b3;
        areaSorted[r] = fmul(fsub(b2,b0), fsub(b3,b1));
        keySorted[r]  = ki;
    }

    if (blockIdx.x == 0) {
        __syncthreads();
        float ninf = -__builtin_inff();
        int inv = 0;
        for (int j = tid; j < N; j += 256) inv += (lkey[j] == ninf);
        part[tid] = inv;
        __syncthreads();
        if (tid == 0) {
            int t = 0;
            for (int q = 0; q < 256; ++q) t += part[q];
            nValidPtr[0] = N - t;
        }
    }
}

// K3: suppression bitmask, ROW-MAJOR padded: mask[i*Wpad + w]; rows 16B-aligned.
// dq[i*4 + d] = mask word (i>>6)+d of row i (d=0..3; 0 if out of range).
__global__ __launch_bounds__(256) void k_mask(
    const float* __restrict__ bs, const float* __restrict__ areas,
    const float* __restrict__ keySorted, unsigned long long* __restrict__ mask,
    unsigned long long* __restrict__ dq,
    int N, int W, int Wpad)
{
    int wid  = threadIdx.x >> 6;
    int lane = threadIdx.x & 63;
    int i = blockIdx.x * 4 + wid;
    if (i >= N) return;
    if (keySorted[i] == -__builtin_inff()) return;   // invalid row: never read
    float ax1 = bs[i*4+0], ay1 = bs[i*4+1], ax2 = bs[i*4+2], ay2 = bs[i*4+3];
    float aa  = areas[i];
    int w0 = i >> 6;
    if (lane == 0) {
        dq[i*4+0] = 0ULL; dq[i*4+1] = 0ULL; dq[i*4+2] = 0ULL; dq[i*4+3] = 0ULL;
    }
    for (int w = w0; w < W; ++w) {
        int j = w*64 + lane;
        int bit = 0;
        if (j < N && j > i) {
            float bx1 = bs[j*4+0], by1 = bs[j*4+1], bx2 = bs[j*4+2], by2 = bs[j*4+3];
            float ba  = areas[j];
            float ix1 = fmaxf(ax1,bx1), iy1 = fmaxf(ay1,by1);
            float ix2 = fminf(ax2,bx2), iy2 = fminf(ay2,by2);
            float iw = fmaxf(fsub(ix2,ix1), 0.0f);
            float ih = fmaxf(fsub(iy2,iy1), 0.0f);
            float inter = fmul(iw, ih);
            float denom = fadd(fsub(fadd(aa, ba), inter), 1e-9f);
            float iou = inter / denom;
            bit = (iou > NMS_THR) ? 1 : 0;
        }
        unsigned long long bm = __ballot(bit);
        if (lane == 0) {
            mask[(long)i*Wpad + w] = bm;
            int d = w - w0;
            if (d < 4) dq[i*4+d] = bm;
        }
    }
}

// K4: wave-specialized greedy scan, 128-row chunks. 1 resolver wave + NACC
// accumulator waves, raw lgkmcnt-only barriers.
// Resolver: per-lane diagonal quads A (row base+lane: words 2c..2c+3) and
// B (row base+64+lane: words 2c+1..2c+4). inc made wave-uniform via
// readfirstlane -> resolve chain is SALU (s_ff1 + v_readlane + s_andn2).
// Two phases: first-half rows then second-half (strictly increasing index =
// exact greedy). sacc(A2,A3 / B1,B2) = kept rows' contribution to next
// chunk's two inc words. Acc waves: 16-bit deal slices; lane L owns words
// 2L,2L+1; word pair (2c+2,2c+3) published by lane c+1 between barriers.
__global__ __launch_bounds__((NACC+1)*64, 1) void k_scan(
    const unsigned long long* __restrict__ mask,
    const unsigned long long* __restrict__ dq,
    const int* __restrict__ nValidPtr,
    int* __restrict__ keepSorted, int N, int W, int Wpad)
{
    __shared__ unsigned long long ldsPartA[NACC+1];
    __shared__ unsigned long long ldsPartB[NACC+1];
    __shared__ unsigned long long ldsKeepLo, ldsKeepHi;
    int tid  = threadIdx.x;
    int wid  = tid >> 6;
    int lane = tid & 63;
    for (int i = tid; i < N; i += (NACC+1)*64) keepSorted[i] = 0;
    if (tid <= NACC) { ldsPartA[tid] = 0ULL; ldsPartB[tid] = 0ULL; }
    if (tid == 0) { ldsKeepLo = 0ULL; ldsKeepHi = 0ULL; }
    __syncthreads();

    int nValid  = __builtin_amdgcn_readfirstlane(nValidPtr[0]);
    int nChunks = (nValid + 127) >> 7;

    // resolver state: diagonal quads for current chunk
    unsigned long long A0=0,A1=0,A2=0,A3=0,B0=0,B1=0,B2=0,B3=0;
    unsigned long long sacc_prevA = 0ULL, sacc_prevB = 0ULL;
    if (wid == 0) {
        int rA = lane, rB = 64 + lane;
        if (rA < N && nChunks > 0) {
            ulonglong2 a01 = *(const ulonglong2*)(dq + (size_t)rA*4);
            ulonglong2 a23 = *(const ulonglong2*)(dq + (size_t)rA*4 + 2);
            A0=a01.x; A1=a01.y; A2=a23.x; A3=a23.y;
        }
        if (rB < N && nChunks > 0) {
            ulonglong2 b01 = *(const ulonglong2*)(dq + (size_t)rB*4);
            ulonglong2 b23 = *(const ulonglong2*)(dq + (size_t)rB*4 + 2);
            B0=b01.x; B1=b01.y; B2=b23.x; B3=b23.y;
        }
    }
    // accumulator state: lane L owns words 2L, 2L+1
    unsigned long long accx = 0ULL, accy = 0ULL;
    bool accWave = (wid >= 1);
    int  accIdx  = wid - 1;                  // 0..NACC-1
    bool laneok  = (2*lane + 1 < Wpad);

    for (int c = 0; c < nChunks; ++c) {
        int base = c << 7;
        if (wid == 0) {
            // prefetch next chunk's quads (vmem, stays in flight across barriers)
            unsigned long long nA0=0,nA1=0,nA2=0,nA3=0,nB0=0,nB1=0,nB2=0,nB3=0;
            if (c + 1 < nChunks) {
                int rA = base + 128 + lane, rB = base + 192 + lane;
                if (rA < N) {
                    ulonglong2 a01 = *(const ulonglong2*)(dq + (size_t)rA*4);
                    ulonglong2 a23 = *(const ulonglong2*)(dq + (size_t)rA*4 + 2);
                    nA0=a01.x; nA1=a01.y; nA2=a23.x; nA3=a23.y;
                }
                if (rB < N) {
                    ulonglong2 b01 = *(const ulonglong2*)(dq + (size_t)rB*4);
                    ulonglong2 b23 = *(const ulonglong2*)(dq + (size_t)rB*4 + 2);
                    nB0=b01.x; nB1=b01.y; nB2=b23.x; nB3=b23.y;
                }
            }

            unsigned long long pA = sacc_prevA, pB = sacc_prevB;
#pragma unroll
            for (int k = 1; k <= NACC; ++k) { pA |= ldsPartA[k]; pB |= ldsPartB[k]; }
            // uniform inc -> SALU resolve chain
            unsigned long long incLo = rfl64(pA), incHi = rfl64(pB);
            int nv  = nValid - base;
            unsigned long long validLo = (nv >= 64) ? ~0ULL : ((1ULL << nv) - 1ULL);
            int nv2 = nv - 64;
            unsigned long long validHi = (nv2 >= 64) ? ~0ULL
                                        : (nv2 <= 0 ? 0ULL : ((1ULL << nv2) - 1ULL));
            unsigned long long candLo = validLo & ~incLo;
            unsigned long long candHi = validHi & ~incHi;
            unsigned long long keepLo = 0ULL, keepHi = 0ULL, sA = 0ULL, sB = 0ULL;
            while (candLo) {                   // phase 1: first-half rows
                int a = __builtin_ctzll(candLo);
                keepLo |= 1ULL << a;
                unsigned long long dFH = rdlane64(A0, a);
                unsigned long long dSH = rdlane64(A1, a);
                sA |= rdlane64(A2, a);
                sB |= rdlane64(A3, a);
                candLo &= ~(1ULL << a) & ~dFH;
                candHi &= ~dSH;
            }
            while (candHi) {                   // phase 2: second-half rows
                int a = __builtin_ctzll(candHi);
                keepHi |= 1ULL << a;
                unsigned long long dSH = rdlane64(B0, a);
                sA |= rdlane64(B1, a);
                sB |= rdlane64(B2, a);
                candHi &= ~(1ULL << a) & ~dSH;
            }
            sacc_prevA = sA; sacc_prevB = sB;
            if (lane == 0) { ldsKeepLo = keepLo; ldsKeepHi = keepHi; }
            if (base + lane < N)      keepSorted[base + lane]      = (int)((keepLo >> lane) & 1ULL);
            if (base + 64 + lane < N) keepSorted[base + 64 + lane] = (int)((keepHi >> lane) & 1ULL);
            A0=nA0; A1=nA1; A2=nA2; A3=nA3; B0=nB0; B1=nB1; B2=nB2; B3=nB3;
        }
        BAR_LDS();                             // barrier A (LDS-order only)
        unsigned long long kLo = ldsKeepLo;
        unsigned long long kHi = ldsKeepHi;
        if (accWave && laneok && lane == c + 1) {  // publish words 2c+2, 2c+3
            ldsPartA[wid] = accx;
            ldsPartB[wid] = accy;
        }
        BAR_LDS();                             // barrier B
        if (accWave && laneok) {
            // 16-bit deal slice: wave accIdx owns keep bits [16k, 16k+16)
            unsigned int myb = (accIdx < 4)
                ? (unsigned int)((kLo >> (16*accIdx)) & 0xFFFFULL)
                : (unsigned int)((kHi >> (16*(accIdx-4))) & 0xFFFFULL);
            if (myb) {
                const unsigned long long* mb =
                    mask + (size_t)(base + 16*accIdx) * Wpad + 2*lane;
                unsigned int b = myb;
                int a0 = __builtin_ctz(b); b &= b - 1;
                int a1 = -1, a2 = -1, a3 = -1;
                if (b) { a1 = __builtin_ctz(b); b &= b - 1; }
                if (b) { a2 = __builtin_ctz(b); b &= b - 1; }
                if (b) { a3 = __builtin_ctz(b); b &= b - 1; }
                ulonglong2 v0 = {0,0}, v1 = {0,0}, v2 = {0,0}, v3 = {0,0};
                v0 = *(const ulonglong2*)(mb + (size_t)a0 * Wpad);
                if (a1 >= 0) v1 = *(const ulonglong2*)(mb + (size_t)a1 * Wpad);
                if (a2 >= 0) v2 = *(const ulonglong2*)(mb + (size_t)a2 * Wpad);
                if (a3 >= 0) v3 = *(const ulonglong2*)(mb + (size_t)a3 * Wpad);
                accx |= (v0.x | v1.x) | (v2.x | v3.x);
                accy |= (v0.y | v1.y) | (v2.y | v3.y);
                while (b) {                    // >4 kept in this slice (rare)
                    int a = __builtin_ctz(b); b &= b - 1;
                    ulonglong2 v = *(const ulonglong2*)(mb + (size_t)a * Wpad);
                    accx |= v.x; accy |= v.y;
                }
            }
        }
    }
}

// K5: write outputs in original order: boxes*m, score*m, float(cls*keep).
__global__ __launch_bounds__(256) void k_out(
    const float* __restrict__ boxes, const float* __restrict__ score,
    const int* __restrict__ cls, const int* __restrict__ rank,
    const int* __restrict__ keepSorted,
    float* __restrict__ out, int N)
{
    int n = blockIdx.x * blockDim.x + threadIdx.x;
    if (n >= N) return;
    int k = keepSorted[rank[n]];
    float m = (float)k;
    out[n*4+0] = boxes[n*4+0]*m;
    out[n*4+1] = boxes[n*4+1]*m;
    out[n*4+2] = boxes[n*4+2]*m;
    out[n*4+3] = boxes[n*4+3]*m;
    out[(long)N*4 + n] = score[n]*m;
    out[(long)N*5 + n] = (float)(cls[n] * k);
}

extern "C" void kernel_launch(void* const* d_in, const int* in_sizes, int n_in,
                              void* d_out, int out_size, void* d_ws, size_t ws_size,
                              hipStream_t stream) {
    const float* prop = (const float*)d_in[0];
    const float* reg  = (const float*)d_in[1];
    const float* clss = (const float*)d_in[2];
    const float* stds = (const float*)d_in[3];
    const int*   img  = (const int*)d_in[4];

    int N = in_sizes[0] / 4;
    int C = in_sizes[2] / N;
    int W = (N + 63) / 64;
    int Wpad = (W + 1) & ~1;          // even -> 16B rows

    char* ws = (char*)d_ws;
    size_t off = 0;
    float* boxes       = (float*)(ws + off); off += (size_t)N*4*sizeof(float);
    float* key         = (float*)(ws + off); off += (size_t)N*sizeof(float);
    float* score       = (float*)(ws + off); off += (size_t)N*sizeof(float);
    int*   cls         = (int*)  (ws + off); off += (size_t)N*sizeof(int);
    int*   rank        = (int*)  (ws + off); off += (size_t)N*sizeof(int);
    float* boxesSorted = (float*)(ws + off); off += (size_t)N*4*sizeof(float);
    float* areaSorted  = (float*)(ws + off); off += (size_t)N*sizeof(float);
    float* keySorted   = (float*)(ws + off); off += (size_t)N*sizeof(float);
    int*   keepSorted  = (int*)  (ws + off); off += (size_t)N*sizeof(int);
    int*   nValid      = (int*)  (ws + off); off += sizeof(int);
    off = (off + 31) & ~(size_t)31;   // 32B-align dq / mask rows
    unsigned long long* dq    = (unsigned long long*)(ws + off);
    off += (size_t)N * 4 * sizeof(unsigned long long);
    unsigned long long* mask  = (unsigned long long*)(ws + off);
    off += (size_t)N * Wpad * sizeof(unsigned long long);
    (void)ws_size; (void)out_size; (void)n_in;

    int rowBlocks  = (N + 3) / 4;
    int thrBlocks  = (N + 255) / 256;
    int rankBlocks = (N + 63) / 64;

    k_decode<<<rowBlocks, 256, 0, stream>>>(prop, reg, clss, stds, img,
                                            boxes, key, score, cls, N, C);
    k_rank<<<rankBlocks, 256, (size_t)N*sizeof(float), stream>>>(key, boxes,
                                            boxesSorted, areaSorted, keySorted, rank, nValid, N);
    k_mask<<<rowBlocks, 256, 0, stream>>>(boxesSorted, areaSorted, keySorted,
                                          mask, dq, N, W, Wpad);
    k_scan<<<1, (NACC+1)*64, 0, stream>>>(mask, dq, nValid, keepSorted, N, W, Wpad);
    k_out<<<thrBlocks, 256, 0, stream>>>(boxes, score, cls, rank, keepSorted,
                                         (float*)d_out, N);
}